// Round 14
// baseline (344.020 us; speedup 1.0000x reference)
//
#include <hip/hip_runtime.h>
#include <stdint.h>

#define S_LEN 2048
#define BSZ   4
#define EMB   1024
#define NH    16
#define HD    64
#define NHEADS (BSZ*NH)
#define M_ROWS (S_LEN*BSZ)
#define R_LORA 16

typedef unsigned short u16t;
typedef __bf16 bf16x8 __attribute__((ext_vector_type(8)));
typedef float  f32x4  __attribute__((ext_vector_type(4)));
typedef float  f32x16 __attribute__((ext_vector_type(16)));
typedef unsigned int uint2v __attribute__((ext_vector_type(2)));

#define QSCALE (0.125f * 1.44269504089f)   // 1/sqrt(64) * log2(e), folded into Wq/bq

__device__ __forceinline__ u16t f2bf(float f){
  union { float f; uint32_t u; } v; v.f = f;
  uint32_t u = v.u;
  u += 0x7FFFu + ((u >> 16) & 1u);   // round-to-nearest-even
  return (u16t)(u >> 16);
}

__device__ __forceinline__ uint32_t cvtpk(float a, float b){
  uint32_t r;
  asm("v_cvt_pk_bf16_f32 %0, %1, %2" : "=v"(r) : "v"(a), "v"(b));
  return r;
}

__device__ __forceinline__ void gload16(const void* g, void* l){
  __builtin_amdgcn_global_load_lds(
    (const __attribute__((address_space(1))) unsigned int*)g,
    (__attribute__((address_space(3))) unsigned int*)l, 16, 0, 0);
}

// GEMM swizzle (16-row read span -> 2-way free): XOR bits 4-6 with row&7
__device__ __forceinline__ int swz(int b){ return b ^ (((b >> 7) & 7) << 4); }
// Attn swizzle (32-row read span): XOR with (row ^ row>>3)&7.
__device__ __forceinline__ int swzA(int b){
  int r = (b >> 7) & 31;
  return b ^ (((r ^ (r >> 3)) & 7) << 4);
}

// ---------------- merged prep: weights (LoRA-folded) + activation converts --
// z 0..2: f32->bf16 convert of x_q/x_k/x_v (2048 blocks each)
// z 3..6: weight prep which=z-3 (first 1024 blocks active)
__global__ __launch_bounds__(256) void k_prep_all(
    const float* __restrict__ xq, const float* __restrict__ xk, const float* __restrict__ xv,
    u16t* __restrict__ oxq, u16t* __restrict__ oxk, u16t* __restrict__ oxv,
    const float* __restrict__ Wq, const float* __restrict__ Aq, const float* __restrict__ Bq,
    const float* __restrict__ Wk,
    const float* __restrict__ Wv, const float* __restrict__ Av, const float* __restrict__ Bv,
    const float* __restrict__ Wo,
    u16t* __restrict__ oq, u16t* __restrict__ ok, u16t* __restrict__ ov, u16t* __restrict__ oo)
{
  int z = blockIdx.y;
  int t = threadIdx.x;
  if (z < 3){
    const float* x = z==0 ? xq : z==1 ? xk : xv;
    u16t* o        = z==0 ? oxq : z==1 ? oxk : oxv;
    const int n = M_ROWS*EMB;
    int stride = gridDim.x * 256 * 4;
    for (int i = (blockIdx.x*256 + t)*4; i < n; i += stride){
      float4 v = *reinterpret_cast<const float4*>(x + i);
      ushort4 u = { f2bf(v.x), f2bf(v.y), f2bf(v.z), f2bf(v.w) };
      *reinterpret_cast<ushort4*>(o + i) = u;
    }
    return;
  }
  if (blockIdx.x >= EMB) return;
  int which = z - 3;
  const float* W = which==0?Wq : which==1?Wk : which==2?Wv : Wo;
  u16t* out      = which==0?oq : which==1?ok : which==2?ov : oo;
  int n = blockIdx.x;
  float4 wv = reinterpret_cast<const float4*>(W + (size_t)n*EMB)[t];
  float add[4] = {0.f, 0.f, 0.f, 0.f};
  if (which == 0 || which == 2){
    const float* A_ = which==0 ? Aq : Av;
    const float* B_ = which==0 ? Bq : Bv;
    float bcol[16];
    #pragma unroll
    for (int r = 0; r < 16; r++) bcol[r] = 2.0f * B_[(size_t)r*EMB + n];
    #pragma unroll
    for (int j = 0; j < 4; j++){
      const float4* ar = reinterpret_cast<const float4*>(A_ + (size_t)(4*t+j)*R_LORA);
      float4 a0 = ar[0], a1 = ar[1], a2 = ar[2], a3 = ar[3];
      add[j] = a0.x*bcol[0] + a0.y*bcol[1] + a0.z*bcol[2] + a0.w*bcol[3]
             + a1.x*bcol[4] + a1.y*bcol[5] + a1.z*bcol[6] + a1.w*bcol[7]
             + a2.x*bcol[8] + a2.y*bcol[9] + a2.z*bcol[10]+ a2.w*bcol[11]
             + a3.x*bcol[12]+ a3.y*bcol[13]+ a3.z*bcol[14]+ a3.w*bcol[15];
    }
  }
  float scale = (which == 0) ? QSCALE : 1.0f;
  ushort4 o = { f2bf((wv.x+add[0])*scale), f2bf((wv.y+add[1])*scale),
                f2bf((wv.z+add[2])*scale), f2bf((wv.w+add[3])*scale) };
  reinterpret_cast<ushort4*>(out + (size_t)n*EMB)[t] = o;
}

// ---------------- shared GEMM main loop: 128x128 tile, BK=64, dbuf --------
__device__ __forceinline__ void gemm_main(
    const u16t* __restrict__ Abase, const u16t* __restrict__ Bbase,
    u16t* smem, int t, int wr, int wc, int l15, int lg, f32x4 (&acc)[4][4]){
  int k0 = 0;
  auto stage = [&](int buf){
    u16t* d = smem + buf*16384;
    #pragma unroll
    for (int i = 0; i < 4; i++){
      int c = i*256 + t;
      int row = c >> 3, ch = c & 7;
      int srcch = ch ^ (row & 7);
      gload16(Abase + (size_t)row*EMB + k0 + srcch*8, d + c*8);
    }
    #pragma unroll
    for (int i = 0; i < 4; i++){
      int c = i*256 + t;
      int row = c >> 3, ch = c & 7;
      int srcch = ch ^ (row & 7);
      gload16(Bbase + (size_t)row*EMB + k0 + srcch*8, d + 8192 + c*8);
    }
    k0 += 64;
  };

  stage(0);
  __syncthreads();    // tile 0 resident

  const int NK = EMB/64;   // 16
  for (int kt = 0; kt < NK; ++kt){
    int cur = kt & 1;
    if (kt+1 < NK) stage(cur^1);     // in flight across this step's compute
    const char* Abuf = (const char*)(smem + cur*16384);
    const char* Bbuf = Abuf + 16384;
    #pragma unroll
    for (int kk = 0; kk < 2; kk++){
      bf16x8 af[4], bfr[4];
      #pragma unroll
      for (int i = 0; i < 4; i++){
        af[i]  = *reinterpret_cast<const bf16x8*>(
            Abuf + swz((wr*64 + i*16 + l15)*128 + kk*64 + lg*16));
        bfr[i] = *reinterpret_cast<const bf16x8*>(
            Bbuf + swz((wc*64 + i*16 + l15)*128 + kk*64 + lg*16));
      }
      __builtin_amdgcn_s_setprio(1);
      #pragma unroll
      for (int mi = 0; mi < 4; mi++)
        #pragma unroll
        for (int ni = 0; ni < 4; ni++)
          acc[mi][ni] = __builtin_amdgcn_mfma_f32_16x16x32_bf16(af[mi], bfr[ni], acc[mi][ni], 0, 0, 0);
      __builtin_amdgcn_s_setprio(0);
    }
    __syncthreads();    // reads of buf[cur] done; stage(kt+1) drained
  }
}

// ---------------- QKV projections, one dispatch (z selects) ---------------
__global__ __launch_bounds__(256) void k_gemm_qkv(
    const u16t* __restrict__ xqb, const u16t* __restrict__ xkb, const u16t* __restrict__ xvb,
    const u16t* __restrict__ Wqb, const u16t* __restrict__ Wkb, const u16t* __restrict__ Wvb,
    const float* __restrict__ bq, const float* __restrict__ bk, const float* __restrict__ bv,
    u16t* __restrict__ q_att, u16t* __restrict__ k_att, u16t* __restrict__ vT)
{
  __shared__ u16t smem[2*16384];   // 64 KB
  int z = blockIdx.z;
  const u16t* A  = z==0 ? xqb : z==1 ? xkb : xvb;
  const u16t* Bw = z==0 ? Wqb : z==1 ? Wkb : Wvb;
  const float* bias = z==0 ? bq : z==1 ? bk : bv;
  float bscale = z==0 ? QSCALE : 1.0f;
  u16t* att = z==0 ? q_att : z==1 ? k_att : vT;

  int t = threadIdx.x;
  int lane = t & 63, w = t >> 6;
  int wr = w >> 1, wc = w & 1;
  int l15 = lane & 15, lg = lane >> 4;
  int m0 = blockIdx.x * 128;
  int n0 = blockIdx.y * 128;

  f32x4 acc[4][4];
  #pragma unroll
  for (int i = 0; i < 4; i++)
    #pragma unroll
    for (int j = 0; j < 4; j++)
      acc[i][j] = (f32x4){0.f, 0.f, 0.f, 0.f};

  gemm_main(A + (size_t)m0*EMB, Bw + (size_t)n0*EMB, smem, t, wr, wc, l15, lg, acc);

  float bval[4];
  #pragma unroll
  for (int ni = 0; ni < 4; ni++)
    bval[ni] = bias[n0 + wc*64 + ni*16 + l15] * bscale;

  if (z < 2){
    // att layout via LDS transpose: smem = [m_local 128][n_local 128] bf16
    #pragma unroll
    for (int mi = 0; mi < 4; mi++)
      #pragma unroll
      for (int ni = 0; ni < 4; ni++)
        #pragma unroll
        for (int j = 0; j < 4; j++){
          int m_local = wr*64 + mi*16 + lg*4 + j;
          int n_local = wc*64 + ni*16 + l15;
          *(u16t*)((char*)smem + swz(m_local*256 + n_local*2)) = f2bf(acc[mi][ni][j] + bval[ni]);
        }
    __syncthreads();
    #pragma unroll
    for (int i = 0; i < 8; i++){
      int c = i*256 + t;              // 2048 chunks of 16B
      int m_local = c >> 4, nch = c & 15;
      uint4 val = *(const uint4*)((const char*)smem + swz(m_local*256 + nch*16));
      int m = m0 + m_local;
      int s = m >> 2, b = m & 3;
      int n = n0 + nch*8;
      int h = n >> 6, d = n & 63;
      *(uint4*)&att[(size_t)((b*NH + h)*S_LEN + s)*HD + d] = val;
    }
  } else {
    // V^T layout via LDS transpose: smem = [n_local 128][m_local 128] bf16
    #pragma unroll
    for (int mi = 0; mi < 4; mi++)
      #pragma unroll
      for (int ni = 0; ni < 4; ni++)
        #pragma unroll
        for (int j = 0; j < 4; j++){
          int m_local = wr*64 + mi*16 + lg*4 + j;
          int n_local = wc*64 + ni*16 + l15;
          *(u16t*)((char*)smem + swz(n_local*256 + m_local*2)) = f2bf(acc[mi][ni][j] + bval[ni]);
        }
    __syncthreads();
    #pragma unroll
    for (int i = 0; i < 8; i++){
      int u = i*256 + t;              // 2048 units: [n 128][b 4][sc 4]
      int dl = u >> 4, b = (u >> 2) & 3, sc = u & 3;
      u16t tmp[8];
      #pragma unroll
      for (int z2 = 0; z2 < 8; z2++)
        tmp[z2] = *(const u16t*)((const char*)smem + swz(dl*256 + ((sc*8+z2)*4 + b)*2));
      int n_glob = n0 + dl;
      int h = n_glob >> 6, d = n_glob & 63;
      int s0 = (m0 >> 2) + sc*8;
      *(uint4*)&att[((size_t)((b*NH + h)*HD + d))*S_LEN + s0] = *(const uint4*)tmp;
    }
  }
}

// ---------------- output projection: f32 out + bias ----------------------
__global__ __launch_bounds__(256) void k_gemm_o(
    const u16t* __restrict__ A, const u16t* __restrict__ Bw,
    const float* __restrict__ bias, float* __restrict__ Cout)
{
  __shared__ u16t smem[2*16384];
  int t = threadIdx.x;
  int lane = t & 63, w = t >> 6;
  int wr = w >> 1, wc = w & 1;
  int l15 = lane & 15, lg = lane >> 4;
  int m0 = blockIdx.x * 128;
  int n0 = blockIdx.y * 128;

  f32x4 acc[4][4];
  #pragma unroll
  for (int i = 0; i < 4; i++)
    #pragma unroll
    for (int j = 0; j < 4; j++)
      acc[i][j] = (f32x4){0.f, 0.f, 0.f, 0.f};

  gemm_main(A + (size_t)m0*EMB, Bw + (size_t)n0*EMB, smem, t, wr, wc, l15, lg, acc);

  float bval[4];
  #pragma unroll
  for (int ni = 0; ni < 4; ni++)
    bval[ni] = bias[n0 + wc*64 + ni*16 + l15];

  #pragma unroll
  for (int mi = 0; mi < 4; mi++){
    #pragma unroll
    for (int j = 0; j < 4; j++){
      int m = m0 + wr*64 + mi*16 + lg*4 + j;
      #pragma unroll
      for (int ni = 0; ni < 4; ni++){
        int n = n0 + wc*64 + ni*16 + l15;
        Cout[(size_t)m*EMB + n] = acc[mi][ni][j] + bval[ni];
      }
    }
  }
}

// ---------------- flash attention (static LDS addressing, unroll-2) -------
// __launch_bounds__(256, 5): cap VGPR at 102 -> 5 blocks/CU (was 4, VGPR=104)
__global__ __launch_bounds__(256, 5) void k_attn(
    const u16t* __restrict__ Qa, const u16t* __restrict__ Ka,
    const u16t* __restrict__ VTa, u16t* __restrict__ Oa)
{
  __shared__ u16t smem[2*8192];   // [buf][K 8KB | Vt 8KB]; buf0 reused as Obuf
  int t = threadIdx.x;
  int lane = t & 63, w = t >> 6;
  int l31 = lane & 31, hi = lane >> 5;
  int head = blockIdx.x;
  int qw = blockIdx.y*128 + w*32;
  const u16t* Qh = Qa + (size_t)head * S_LEN * HD;
  const char* Khc = (const char*)(Ka + (size_t)head * S_LEN * HD);
  const char* VTc = (const char*)(VTa + (size_t)head * HD * S_LEN);

  bf16x8 qf[4];
  #pragma unroll
  for (int ds = 0; ds < 4; ds++)
    qf[ds] = *reinterpret_cast<const bf16x8*>(
        Qh + (size_t)(qw + l31)*HD + ds*16 + hi*8);

  bf16x8 ones;
  { union { uint32_t u[4]; bf16x8 v; } o;
    o.u[0]=o.u[1]=o.u[2]=o.u[3]=0x3F803F80u; ones = o.v; }

  f32x16 oacc[2], lacc;
  oacc[0] = (f32x16)(0.f); oacc[1] = (f32x16)(0.f); lacc = (f32x16)(0.f);

  // precomputed fragment-read offsets (K and V share the same pattern)
  int off[8];
  #pragma unroll
  for (int x = 0; x < 2; x++)
    #pragma unroll
    for (int y = 0; y < 4; y++)
      off[x*4+y] = swzA((x*32 + l31)*128 + y*32 + hi*16);

  // precomputed staging source bases (swzA evaluated once)
  int tb0 = swzA(t*16);
  int tb1 = swzA((256+t)*16);
  const char* ks0 = Khc + tb0;
  const char* ks1 = Khc + tb1;
  const char* vs0 = VTc + (size_t)(tb0 >> 7)*(S_LEN*2) + (tb0 & 127);
  const char* vs1 = VTc + (size_t)(tb1 >> 7)*(S_LEN*2) + (tb1 & 127);

  auto stage = [&](int bufbyte, int key0){
    char* dst = (char*)smem + bufbyte;
    gload16(ks0 + (size_t)key0*128, dst + t*16);
    gload16(ks1 + (size_t)key0*128, dst + 4096 + t*16);
    gload16(vs0 + key0*2, dst + 8192 + t*16);
    gload16(vs1 + key0*2, dst + 12288 + t*16);
  };

  auto tile_body = [&](int kbase){
    f32x16 sacc[2];
    sacc[0] = (f32x16)(0.f); sacc[1] = (f32x16)(0.f);
    __builtin_amdgcn_s_setprio(1);
    #pragma unroll
    for (int blk = 0; blk < 2; blk++){
      #pragma unroll
      for (int ds = 0; ds < 4; ds++){
        bf16x8 kf = *reinterpret_cast<const bf16x8*>(
            (const char*)smem + kbase + off[blk*4+ds]);
        sacc[blk] = __builtin_amdgcn_mfma_f32_32x32x16_bf16(kf, qf[ds], sacc[blk], 0,0,0);
      }
    }
    __builtin_amdgcn_s_setprio(0);

    #pragma unroll
    for (int blk = 0; blk < 2; blk++)
      #pragma unroll
      for (int r = 0; r < 16; r++)
        sacc[blk][r] = __builtin_amdgcn_exp2f(sacc[blk][r]);

    bf16x8 pa[4];
    #pragma unroll
    for (int blk = 0; blk < 2; blk++){
      #pragma unroll
      for (int kl = 0; kl < 2; kl++){
        union { uint32_t u[4]; bf16x8 v; } fr;
        #pragma unroll
        for (int i = 0; i < 2; i++){
          uint32_t x = cvtpk(sacc[blk][kl*8 + 2*i],     sacc[blk][kl*8 + 2*i + 1]);
          uint32_t y = cvtpk(sacc[blk][kl*8 + 4 + 2*i], sacc[blk][kl*8 + 4 + 2*i + 1]);
          uint2v r = __builtin_amdgcn_permlane32_swap(x, y, false, false);
          fr.u[i]   = r.x;
          fr.u[i+2] = r.y;
        }
        pa[blk*2 + kl] = fr.v;
      }
    }

    __builtin_amdgcn_s_setprio(1);
    #pragma unroll
    for (int dblk = 0; dblk < 2; dblk++){
      #pragma unroll
      for (int ks = 0; ks < 4; ks++){
        bf16x8 vf = *reinterpret_cast<const bf16x8*>(
            (const char*)smem + kbase + 8192 + off[dblk*4+ks]);
        oacc[dblk] = __builtin_amdgcn_mfma_f32_32x32x16_bf16(vf, pa[ks], oacc[dblk], 0,0,0);
      }
    }
    #pragma unroll
    for (int ks = 0; ks < 4; ks++)
      lacc = __builtin_amdgcn_mfma_f32_32x32x16_bf16(ones, pa[ks], lacc, 0,0,0);
    __builtin_amdgcn_s_setprio(0);
  };

  stage(0, 0);
  __syncthreads();

  const int NT = S_LEN/64;   // 32, even
  for (int nt = 0; nt < NT; nt += 2){
    if (nt+1 < NT) stage(16384, (nt+1)*64);
    tile_body(0);
    __syncthreads();
    if (nt+2 < NT) stage(0, (nt+2)*64);
    tile_body(16384);
    __syncthreads();
  }

  // ---- epilogue: normalize, transpose via LDS (reuse smem buf0), store ----
  float inv = 1.0f / lacc[0];   // every row of lacc tile = sum_k P[k][q=l31]
  #pragma unroll
  for (int dblk = 0; dblk < 2; dblk++){
    #pragma unroll
    for (int rp = 0; rp < 8; rp++){
      int reg = 2*rp;
      int d = dblk*32 + (reg&3) + 8*(reg>>2) + 4*hi;
      uint32_t wv = cvtpk(oacc[dblk][reg]*inv, oacc[dblk][reg+1]*inv);
      *(uint32_t*)((char*)smem + swz((w*32 + l31)*128 + d*2)) = wv;
    }
  }
  __syncthreads();
  int b = head >> 4, h = head & 15;
  #pragma unroll
  for (int i = 0; i < 4; i++){
    int c = i*256 + t;
    int row = c >> 3;
    int col = c & 7;
    uint4 val = *(const uint4*)((const char*)smem + swz(row*128 + col*16));
    int q = blockIdx.y*128 + row;
    *(uint4*)(Oa + (size_t)(q*BSZ + b)*EMB + h*HD + col*8) = val;
  }
}

extern "C" void kernel_launch(void* const* d_in, const int* in_sizes, int n_in,
                              void* d_out, int out_size, void* d_ws, size_t ws_size,
                              hipStream_t stream) {
  const float* x_q = (const float*)d_in[0];
  const float* x_k = (const float*)d_in[1];
  const float* x_v = (const float*)d_in[2];
  const float* Wq  = (const float*)d_in[3];
  const float* bq  = (const float*)d_in[4];
  const float* Aq  = (const float*)d_in[5];
  const float* Bq  = (const float*)d_in[6];
  const float* Wk  = (const float*)d_in[7];
  const float* bk  = (const float*)d_in[8];
  const float* Wv  = (const float*)d_in[9];
  const float* bv  = (const float*)d_in[10];
  const float* Av  = (const float*)d_in[11];
  const float* Bv  = (const float*)d_in[12];
  const float* Wo  = (const float*)d_in[13];
  const float* bo  = (const float*)d_in[14];
  float* out = (float*)d_out;

  char* ws = (char*)d_ws;
  size_t off = 0;
  auto alloc = [&](size_t bytes){
    void* p = ws + off; off += (bytes + 255) & ~(size_t)255; return p;
  };
  u16t* xqb   = (u16t*)alloc((size_t)M_ROWS*EMB*2);   // also reused as attnout
  u16t* xkb   = (u16t*)alloc((size_t)M_ROWS*EMB*2);
  u16t* xvb   = (u16t*)alloc((size_t)M_ROWS*EMB*2);
  u16t* q_att = (u16t*)alloc((size_t)M_ROWS*EMB*2);
  u16t* k_att = (u16t*)alloc((size_t)M_ROWS*EMB*2);
  u16t* vT    = (u16t*)alloc((size_t)M_ROWS*EMB*2);   // V^T [head][d][s]
  u16t* Wqb = (u16t*)alloc((size_t)EMB*EMB*2);
  u16t* Wkb = (u16t*)alloc((size_t)EMB*EMB*2);
  u16t* Wvb = (u16t*)alloc((size_t)EMB*EMB*2);
  u16t* Wob = (u16t*)alloc((size_t)EMB*EMB*2);
  (void)ws_size; (void)in_sizes; (void)n_in; (void)out_size;

  // merged prep: activation converts (z 0..2) + LoRA-folded weight prep (z 3..6)
  k_prep_all<<<dim3(2048, 7), 256, 0, stream>>>(
      x_q, x_k, x_v, xqb, xkb, xvb,
      Wq, Aq, Bq, Wk, Wv, Av, Bv, Wo, Wqb, Wkb, Wvb, Wob);

  // Q/K/V projections in one dispatch (2-phase 128x128, proven)
  k_gemm_qkv<<<dim3(M_ROWS/128, EMB/128, 3), 256, 0, stream>>>(
      xqb, xkb, xvb, Wqb, Wkb, Wvb, bq, bk, bv, q_att, k_att, vT);

  // attention: writes attnout [m][1024] into xqb (free by now)
  k_attn<<<dim3(NHEADS, S_LEN/128), 256, 0, stream>>>(q_att, k_att, vT, xqb);

  // output projection (f32 + bias)
  k_gemm_o<<<dim3(M_ROWS/128, EMB/128), 256, 0, stream>>>(xqb, Wob, bo, out);
}

// Round 15
// 223.388 us; speedup vs baseline: 1.5400x; 1.5400x over previous
//
#include <hip/hip_runtime.h>
#include <stdint.h>

#define S_LEN 2048
#define BSZ   4
#define EMB   1024
#define NH    16
#define HD    64
#define NHEADS (BSZ*NH)
#define M_ROWS (S_LEN*BSZ)
#define R_LORA 16

typedef unsigned short u16t;
typedef __bf16 bf16x8 __attribute__((ext_vector_type(8)));
typedef float  f32x4  __attribute__((ext_vector_type(4)));
typedef float  f32x16 __attribute__((ext_vector_type(16)));
typedef unsigned int uint2v __attribute__((ext_vector_type(2)));

#define QSCALE (0.125f * 1.44269504089f)   // 1/sqrt(64) * log2(e), folded into Wq/bq

__device__ __forceinline__ u16t f2bf(float f){
  union { float f; uint32_t u; } v; v.f = f;
  uint32_t u = v.u;
  u += 0x7FFFu + ((u >> 16) & 1u);   // round-to-nearest-even
  return (u16t)(u >> 16);
}

__device__ __forceinline__ uint32_t cvtpk(float a, float b){
  uint32_t r;
  asm("v_cvt_pk_bf16_f32 %0, %1, %2" : "=v"(r) : "v"(a), "v"(b));
  return r;
}

__device__ __forceinline__ void gload16(const void* g, void* l){
  __builtin_amdgcn_global_load_lds(
    (const __attribute__((address_space(1))) unsigned int*)g,
    (__attribute__((address_space(3))) unsigned int*)l, 16, 0, 0);
}

// GEMM swizzle (16-row read span -> 2-way free): XOR bits 4-6 with row&7
__device__ __forceinline__ int swz(int b){ return b ^ (((b >> 7) & 7) << 4); }
// Attn swizzle (32-row read span): XOR with (row ^ row>>3)&7.
__device__ __forceinline__ int swzA(int b){
  int r = (b >> 7) & 31;
  return b ^ (((r ^ (r >> 3)) & 7) << 4);
}

// ---------------- merged prep: weights (LoRA-folded) + activation converts --
// z 0..2: f32->bf16 convert of x_q/x_k/x_v (2048 blocks each)
// z 3..6: weight prep which=z-3 (first 1024 blocks active)
__global__ __launch_bounds__(256) void k_prep_all(
    const float* __restrict__ xq, const float* __restrict__ xk, const float* __restrict__ xv,
    u16t* __restrict__ oxq, u16t* __restrict__ oxk, u16t* __restrict__ oxv,
    const float* __restrict__ Wq, const float* __restrict__ Aq, const float* __restrict__ Bq,
    const float* __restrict__ Wk,
    const float* __restrict__ Wv, const float* __restrict__ Av, const float* __restrict__ Bv,
    const float* __restrict__ Wo,
    u16t* __restrict__ oq, u16t* __restrict__ ok, u16t* __restrict__ ov, u16t* __restrict__ oo)
{
  int z = blockIdx.y;
  int t = threadIdx.x;
  if (z < 3){
    const float* x = z==0 ? xq : z==1 ? xk : xv;
    u16t* o        = z==0 ? oxq : z==1 ? oxk : oxv;
    const int n = M_ROWS*EMB;
    int stride = gridDim.x * 256 * 4;
    for (int i = (blockIdx.x*256 + t)*4; i < n; i += stride){
      float4 v = *reinterpret_cast<const float4*>(x + i);
      ushort4 u = { f2bf(v.x), f2bf(v.y), f2bf(v.z), f2bf(v.w) };
      *reinterpret_cast<ushort4*>(o + i) = u;
    }
    return;
  }
  if (blockIdx.x >= EMB) return;
  int which = z - 3;
  const float* W = which==0?Wq : which==1?Wk : which==2?Wv : Wo;
  u16t* out      = which==0?oq : which==1?ok : which==2?ov : oo;
  int n = blockIdx.x;
  float4 wv = reinterpret_cast<const float4*>(W + (size_t)n*EMB)[t];
  float add[4] = {0.f, 0.f, 0.f, 0.f};
  if (which == 0 || which == 2){
    const float* A_ = which==0 ? Aq : Av;
    const float* B_ = which==0 ? Bq : Bv;
    float bcol[16];
    #pragma unroll
    for (int r = 0; r < 16; r++) bcol[r] = 2.0f * B_[(size_t)r*EMB + n];
    #pragma unroll
    for (int j = 0; j < 4; j++){
      const float4* ar = reinterpret_cast<const float4*>(A_ + (size_t)(4*t+j)*R_LORA);
      float4 a0 = ar[0], a1 = ar[1], a2 = ar[2], a3 = ar[3];
      add[j] = a0.x*bcol[0] + a0.y*bcol[1] + a0.z*bcol[2] + a0.w*bcol[3]
             + a1.x*bcol[4] + a1.y*bcol[5] + a1.z*bcol[6] + a1.w*bcol[7]
             + a2.x*bcol[8] + a2.y*bcol[9] + a2.z*bcol[10]+ a2.w*bcol[11]
             + a3.x*bcol[12]+ a3.y*bcol[13]+ a3.z*bcol[14]+ a3.w*bcol[15];
    }
  }
  float scale = (which == 0) ? QSCALE : 1.0f;
  ushort4 o = { f2bf((wv.x+add[0])*scale), f2bf((wv.y+add[1])*scale),
                f2bf((wv.z+add[2])*scale), f2bf((wv.w+add[3])*scale) };
  reinterpret_cast<ushort4*>(out + (size_t)n*EMB)[t] = o;
}

// ---------------- shared GEMM main loop: 128x128 tile, BK=64, dbuf --------
__device__ __forceinline__ void gemm_main(
    const u16t* __restrict__ Abase, const u16t* __restrict__ Bbase,
    u16t* smem, int t, int wr, int wc, int l15, int lg, f32x4 (&acc)[4][4]){
  int k0 = 0;
  auto stage = [&](int buf){
    u16t* d = smem + buf*16384;
    #pragma unroll
    for (int i = 0; i < 4; i++){
      int c = i*256 + t;
      int row = c >> 3, ch = c & 7;
      int srcch = ch ^ (row & 7);
      gload16(Abase + (size_t)row*EMB + k0 + srcch*8, d + c*8);
    }
    #pragma unroll
    for (int i = 0; i < 4; i++){
      int c = i*256 + t;
      int row = c >> 3, ch = c & 7;
      int srcch = ch ^ (row & 7);
      gload16(Bbase + (size_t)row*EMB + k0 + srcch*8, d + 8192 + c*8);
    }
    k0 += 64;
  };

  stage(0);
  __syncthreads();    // tile 0 resident

  const int NK = EMB/64;   // 16
  for (int kt = 0; kt < NK; ++kt){
    int cur = kt & 1;
    if (kt+1 < NK) stage(cur^1);     // in flight across this step's compute
    const char* Abuf = (const char*)(smem + cur*16384);
    const char* Bbuf = Abuf + 16384;
    #pragma unroll
    for (int kk = 0; kk < 2; kk++){
      bf16x8 af[4], bfr[4];
      #pragma unroll
      for (int i = 0; i < 4; i++){
        af[i]  = *reinterpret_cast<const bf16x8*>(
            Abuf + swz((wr*64 + i*16 + l15)*128 + kk*64 + lg*16));
        bfr[i] = *reinterpret_cast<const bf16x8*>(
            Bbuf + swz((wc*64 + i*16 + l15)*128 + kk*64 + lg*16));
      }
      __builtin_amdgcn_s_setprio(1);
      #pragma unroll
      for (int mi = 0; mi < 4; mi++)
        #pragma unroll
        for (int ni = 0; ni < 4; ni++)
          acc[mi][ni] = __builtin_amdgcn_mfma_f32_16x16x32_bf16(af[mi], bfr[ni], acc[mi][ni], 0, 0, 0);
      __builtin_amdgcn_s_setprio(0);
    }
    __syncthreads();    // reads of buf[cur] done; stage(kt+1) drained
  }
}

// ---------------- QKV projections, one dispatch (z selects) ---------------
__global__ __launch_bounds__(256) void k_gemm_qkv(
    const u16t* __restrict__ xqb, const u16t* __restrict__ xkb, const u16t* __restrict__ xvb,
    const u16t* __restrict__ Wqb, const u16t* __restrict__ Wkb, const u16t* __restrict__ Wvb,
    const float* __restrict__ bq, const float* __restrict__ bk, const float* __restrict__ bv,
    u16t* __restrict__ q_att, u16t* __restrict__ k_att, u16t* __restrict__ vT)
{
  __shared__ u16t smem[2*16384];   // 64 KB
  int z = blockIdx.z;
  const u16t* A  = z==0 ? xqb : z==1 ? xkb : xvb;
  const u16t* Bw = z==0 ? Wqb : z==1 ? Wkb : Wvb;
  const float* bias = z==0 ? bq : z==1 ? bk : bv;
  float bscale = z==0 ? QSCALE : 1.0f;
  u16t* att = z==0 ? q_att : z==1 ? k_att : vT;

  int t = threadIdx.x;
  int lane = t & 63, w = t >> 6;
  int wr = w >> 1, wc = w & 1;
  int l15 = lane & 15, lg = lane >> 4;
  int m0 = blockIdx.x * 128;
  int n0 = blockIdx.y * 128;

  f32x4 acc[4][4];
  #pragma unroll
  for (int i = 0; i < 4; i++)
    #pragma unroll
    for (int j = 0; j < 4; j++)
      acc[i][j] = (f32x4){0.f, 0.f, 0.f, 0.f};

  gemm_main(A + (size_t)m0*EMB, Bw + (size_t)n0*EMB, smem, t, wr, wc, l15, lg, acc);

  float bval[4];
  #pragma unroll
  for (int ni = 0; ni < 4; ni++)
    bval[ni] = bias[n0 + wc*64 + ni*16 + l15] * bscale;

  if (z < 2){
    // att layout via LDS transpose: smem = [m_local 128][n_local 128] bf16
    #pragma unroll
    for (int mi = 0; mi < 4; mi++)
      #pragma unroll
      for (int ni = 0; ni < 4; ni++)
        #pragma unroll
        for (int j = 0; j < 4; j++){
          int m_local = wr*64 + mi*16 + lg*4 + j;
          int n_local = wc*64 + ni*16 + l15;
          *(u16t*)((char*)smem + swz(m_local*256 + n_local*2)) = f2bf(acc[mi][ni][j] + bval[ni]);
        }
    __syncthreads();
    #pragma unroll
    for (int i = 0; i < 8; i++){
      int c = i*256 + t;              // 2048 chunks of 16B
      int m_local = c >> 4, nch = c & 15;
      uint4 val = *(const uint4*)((const char*)smem + swz(m_local*256 + nch*16));
      int m = m0 + m_local;
      int s = m >> 2, b = m & 3;
      int n = n0 + nch*8;
      int h = n >> 6, d = n & 63;
      *(uint4*)&att[(size_t)((b*NH + h)*S_LEN + s)*HD + d] = val;
    }
  } else {
    // V^T layout via LDS transpose: smem = [n_local 128][m_local 128] bf16
    #pragma unroll
    for (int mi = 0; mi < 4; mi++)
      #pragma unroll
      for (int ni = 0; ni < 4; ni++)
        #pragma unroll
        for (int j = 0; j < 4; j++){
          int m_local = wr*64 + mi*16 + lg*4 + j;
          int n_local = wc*64 + ni*16 + l15;
          *(u16t*)((char*)smem + swz(n_local*256 + m_local*2)) = f2bf(acc[mi][ni][j] + bval[ni]);
        }
    __syncthreads();
    #pragma unroll
    for (int i = 0; i < 8; i++){
      int u = i*256 + t;              // 2048 units: [n 128][b 4][sc 4]
      int dl = u >> 4, b = (u >> 2) & 3, sc = u & 3;
      u16t tmp[8];
      #pragma unroll
      for (int z2 = 0; z2 < 8; z2++)
        tmp[z2] = *(const u16t*)((const char*)smem + swz(dl*256 + ((sc*8+z2)*4 + b)*2));
      int n_glob = n0 + dl;
      int h = n_glob >> 6, d = n_glob & 63;
      int s0 = (m0 >> 2) + sc*8;
      *(uint4*)&att[((size_t)((b*NH + h)*HD + d))*S_LEN + s0] = *(const uint4*)tmp;
    }
  }
}

// ---------------- output projection: f32 out + bias ----------------------
__global__ __launch_bounds__(256) void k_gemm_o(
    const u16t* __restrict__ A, const u16t* __restrict__ Bw,
    const float* __restrict__ bias, float* __restrict__ Cout)
{
  __shared__ u16t smem[2*16384];
  int t = threadIdx.x;
  int lane = t & 63, w = t >> 6;
  int wr = w >> 1, wc = w & 1;
  int l15 = lane & 15, lg = lane >> 4;
  int m0 = blockIdx.x * 128;
  int n0 = blockIdx.y * 128;

  f32x4 acc[4][4];
  #pragma unroll
  for (int i = 0; i < 4; i++)
    #pragma unroll
    for (int j = 0; j < 4; j++)
      acc[i][j] = (f32x4){0.f, 0.f, 0.f, 0.f};

  gemm_main(A + (size_t)m0*EMB, Bw + (size_t)n0*EMB, smem, t, wr, wc, l15, lg, acc);

  float bval[4];
  #pragma unroll
  for (int ni = 0; ni < 4; ni++)
    bval[ni] = bias[n0 + wc*64 + ni*16 + l15];

  #pragma unroll
  for (int mi = 0; mi < 4; mi++){
    #pragma unroll
    for (int j = 0; j < 4; j++){
      int m = m0 + wr*64 + mi*16 + lg*4 + j;
      #pragma unroll
      for (int ni = 0; ni < 4; ni++){
        int n = n0 + wc*64 + ni*16 + l15;
        Cout[(size_t)m*EMB + n] = acc[mi][ni][j] + bval[ni];
      }
    }
  }
}

// ---------------- flash attention (static LDS addressing, unroll-2) -------
__global__ __launch_bounds__(256) void k_attn(
    const u16t* __restrict__ Qa, const u16t* __restrict__ Ka,
    const u16t* __restrict__ VTa, u16t* __restrict__ Oa)
{
  __shared__ u16t smem[2*8192];   // [buf][K 8KB | Vt 8KB]; buf0 reused as Obuf
  int t = threadIdx.x;
  int lane = t & 63, w = t >> 6;
  int l31 = lane & 31, hi = lane >> 5;
  int head = blockIdx.x;
  int qw = blockIdx.y*128 + w*32;
  const u16t* Qh = Qa + (size_t)head * S_LEN * HD;
  const char* Khc = (const char*)(Ka + (size_t)head * S_LEN * HD);
  const char* VTc = (const char*)(VTa + (size_t)head * HD * S_LEN);

  bf16x8 qf[4];
  #pragma unroll
  for (int ds = 0; ds < 4; ds++)
    qf[ds] = *reinterpret_cast<const bf16x8*>(
        Qh + (size_t)(qw + l31)*HD + ds*16 + hi*8);

  bf16x8 ones;
  { union { uint32_t u[4]; bf16x8 v; } o;
    o.u[0]=o.u[1]=o.u[2]=o.u[3]=0x3F803F80u; ones = o.v; }

  f32x16 oacc[2], lacc;
  oacc[0] = (f32x16)(0.f); oacc[1] = (f32x16)(0.f); lacc = (f32x16)(0.f);

  // precomputed fragment-read offsets (K and V share the same pattern)
  int off[8];
  #pragma unroll
  for (int x = 0; x < 2; x++)
    #pragma unroll
    for (int y = 0; y < 4; y++)
      off[x*4+y] = swzA((x*32 + l31)*128 + y*32 + hi*16);

  // precomputed staging source bases (swzA evaluated once)
  int tb0 = swzA(t*16);
  int tb1 = swzA((256+t)*16);
  const char* ks0 = Khc + tb0;
  const char* ks1 = Khc + tb1;
  const char* vs0 = VTc + (size_t)(tb0 >> 7)*(S_LEN*2) + (tb0 & 127);
  const char* vs1 = VTc + (size_t)(tb1 >> 7)*(S_LEN*2) + (tb1 & 127);

  auto stage = [&](int bufbyte, int key0){
    char* dst = (char*)smem + bufbyte;
    gload16(ks0 + (size_t)key0*128, dst + t*16);
    gload16(ks1 + (size_t)key0*128, dst + 4096 + t*16);
    gload16(vs0 + key0*2, dst + 8192 + t*16);
    gload16(vs1 + key0*2, dst + 12288 + t*16);
  };

  auto tile_body = [&](int kbase){
    f32x16 sacc[2];
    sacc[0] = (f32x16)(0.f); sacc[1] = (f32x16)(0.f);
    __builtin_amdgcn_s_setprio(1);
    #pragma unroll
    for (int blk = 0; blk < 2; blk++){
      #pragma unroll
      for (int ds = 0; ds < 4; ds++){
        bf16x8 kf = *reinterpret_cast<const bf16x8*>(
            (const char*)smem + kbase + off[blk*4+ds]);
        sacc[blk] = __builtin_amdgcn_mfma_f32_32x32x16_bf16(kf, qf[ds], sacc[blk], 0,0,0);
      }
    }
    __builtin_amdgcn_s_setprio(0);

    #pragma unroll
    for (int blk = 0; blk < 2; blk++)
      #pragma unroll
      for (int r = 0; r < 16; r++)
        sacc[blk][r] = __builtin_amdgcn_exp2f(sacc[blk][r]);

    bf16x8 pa[4];
    #pragma unroll
    for (int blk = 0; blk < 2; blk++){
      #pragma unroll
      for (int kl = 0; kl < 2; kl++){
        union { uint32_t u[4]; bf16x8 v; } fr;
        #pragma unroll
        for (int i = 0; i < 2; i++){
          uint32_t x = cvtpk(sacc[blk][kl*8 + 2*i],     sacc[blk][kl*8 + 2*i + 1]);
          uint32_t y = cvtpk(sacc[blk][kl*8 + 4 + 2*i], sacc[blk][kl*8 + 4 + 2*i + 1]);
          uint2v r = __builtin_amdgcn_permlane32_swap(x, y, false, false);
          fr.u[i]   = r.x;
          fr.u[i+2] = r.y;
        }
        pa[blk*2 + kl] = fr.v;
      }
    }

    __builtin_amdgcn_s_setprio(1);
    #pragma unroll
    for (int dblk = 0; dblk < 2; dblk++){
      #pragma unroll
      for (int ks = 0; ks < 4; ks++){
        bf16x8 vf = *reinterpret_cast<const bf16x8*>(
            (const char*)smem + kbase + 8192 + off[dblk*4+ks]);
        oacc[dblk] = __builtin_amdgcn_mfma_f32_32x32x16_bf16(vf, pa[ks], oacc[dblk], 0,0,0);
      }
    }
    #pragma unroll
    for (int ks = 0; ks < 4; ks++)
      lacc = __builtin_amdgcn_mfma_f32_32x32x16_bf16(ones, pa[ks], lacc, 0,0,0);
    __builtin_amdgcn_s_setprio(0);
  };

  stage(0, 0);
  __syncthreads();

  const int NT = S_LEN/64;   // 32, even
  for (int nt = 0; nt < NT; nt += 2){
    if (nt+1 < NT) stage(16384, (nt+1)*64);
    tile_body(0);
    __syncthreads();
    if (nt+2 < NT) stage(0, (nt+2)*64);
    tile_body(16384);
    __syncthreads();
  }

  // ---- epilogue: normalize, transpose via LDS (reuse smem buf0), store ----
  float inv = 1.0f / lacc[0];   // every row of lacc tile = sum_k P[k][q=l31]
  #pragma unroll
  for (int dblk = 0; dblk < 2; dblk++){
    #pragma unroll
    for (int rp = 0; rp < 8; rp++){
      int reg = 2*rp;
      int d = dblk*32 + (reg&3) + 8*(reg>>2) + 4*hi;
      uint32_t wv = cvtpk(oacc[dblk][reg]*inv, oacc[dblk][reg+1]*inv);
      *(uint32_t*)((char*)smem + swz((w*32 + l31)*128 + d*2)) = wv;
    }
  }
  __syncthreads();
  int b = head >> 4, h = head & 15;
  #pragma unroll
  for (int i = 0; i < 4; i++){
    int c = i*256 + t;
    int row = c >> 3;
    int col = c & 7;
    uint4 val = *(const uint4*)((const char*)smem + swz(row*128 + col*16));
    int q = blockIdx.y*128 + row;
    *(uint4*)(Oa + (size_t)(q*BSZ + b)*EMB + h*HD + col*8) = val;
  }
}

extern "C" void kernel_launch(void* const* d_in, const int* in_sizes, int n_in,
                              void* d_out, int out_size, void* d_ws, size_t ws_size,
                              hipStream_t stream) {
  const float* x_q = (const float*)d_in[0];
  const float* x_k = (const float*)d_in[1];
  const float* x_v = (const float*)d_in[2];
  const float* Wq  = (const float*)d_in[3];
  const float* bq  = (const float*)d_in[4];
  const float* Aq  = (const float*)d_in[5];
  const float* Bq  = (const float*)d_in[6];
  const float* Wk  = (const float*)d_in[7];
  const float* bk  = (const float*)d_in[8];
  const float* Wv  = (const float*)d_in[9];
  const float* bv  = (const float*)d_in[10];
  const float* Av  = (const float*)d_in[11];
  const float* Bv  = (const float*)d_in[12];
  const float* Wo  = (const float*)d_in[13];
  const float* bo  = (const float*)d_in[14];
  float* out = (float*)d_out;

  char* ws = (char*)d_ws;
  size_t off = 0;
  auto alloc = [&](size_t bytes){
    void* p = ws + off; off += (bytes + 255) & ~(size_t)255; return p;
  };
  u16t* xqb   = (u16t*)alloc((size_t)M_ROWS*EMB*2);   // also reused as attnout
  u16t* xkb   = (u16t*)alloc((size_t)M_ROWS*EMB*2);
  u16t* xvb   = (u16t*)alloc((size_t)M_ROWS*EMB*2);
  u16t* q_att = (u16t*)alloc((size_t)M_ROWS*EMB*2);
  u16t* k_att = (u16t*)alloc((size_t)M_ROWS*EMB*2);
  u16t* vT    = (u16t*)alloc((size_t)M_ROWS*EMB*2);   // V^T [head][d][s]
  u16t* Wqb = (u16t*)alloc((size_t)EMB*EMB*2);
  u16t* Wkb = (u16t*)alloc((size_t)EMB*EMB*2);
  u16t* Wvb = (u16t*)alloc((size_t)EMB*EMB*2);
  u16t* Wob = (u16t*)alloc((size_t)EMB*EMB*2);
  (void)ws_size; (void)in_sizes; (void)n_in; (void)out_size;

  // merged prep: activation converts (z 0..2) + LoRA-folded weight prep (z 3..6)
  k_prep_all<<<dim3(2048, 7), 256, 0, stream>>>(
      x_q, x_k, x_v, xqb, xkb, xvb,
      Wq, Aq, Bq, Wk, Wv, Av, Bv, Wo, Wqb, Wkb, Wvb, Wob);

  // Q/K/V projections in one dispatch (2-phase 128x128, proven)
  k_gemm_qkv<<<dim3(M_ROWS/128, EMB/128, 3), 256, 0, stream>>>(
      xqb, xkb, xvb, Wqb, Wkb, Wvb, bq, bk, bv, q_att, k_att, vT);

  // attention: writes attnout [m][1024] into xqb (free by now)
  k_attn<<<dim3(NHEADS, S_LEN/128), 256, 0, stream>>>(q_att, k_att, vT, xqb);

  // output projection (f32 + bias)
  k_gemm_o<<<dim3(M_ROWS/128, EMB/128), 256, 0, stream>>>(xqb, Wob, bo, out);
}